// Round 10
// baseline (169.399 us; speedup 1.0000x reference)
//
#include <hip/hip_runtime.h>
#include <cmath>

#define NN    4096
#define FIN   32
#define KSEL  39      // neighbors kept (top-40 minus self)
#define PP    22
#define PPAD  24
#define FOUT  48
#define WPB   2       // waves per block
#define QW    4       // queries per wave
#define CAP   128     // candidate cap per query (fallback if exceeded)
#define WCOLS 32      // combined weight columns: [Wf(22) | pad(2) | Ws(4) | pad(4)]

#define WSYNC() asm volatile("s_waitcnt lgkmcnt(0)" ::: "memory")

__device__ __forceinline__ int lane_prefix(unsigned long long m) {
    return __builtin_amdgcn_mbcnt_hi((unsigned)(m >> 32),
           __builtin_amdgcn_mbcnt_lo((unsigned)m, 0));
}
// order-preserving float->uint map (total order, handles negatives)
__device__ __forceinline__ unsigned ford(float f) {
    int u = __float_as_int(f);
    return (u >= 0) ? ((unsigned)u | 0x80000000u) : ~(unsigned)u;
}
__device__ __forceinline__ float funord(unsigned k) {
    unsigned v = (k & 0x80000000u) ? (k & 0x7FFFFFFFu) : ~k;
    return __uint_as_float(v);
}
// broadcast lane l's value (l must be wave-uniform; here a literal)
__device__ __forceinline__ float lane_bcast(float v, int l) {
    return __uint_as_float((unsigned)__builtin_amdgcn_readlane((int)__float_as_uint(v), l));
}
// |c|^2 with the EXACT gn_pre FMA order (bit-identical everywhere)
__device__ __forceinline__ float sq4(float4 c) {
    return fmaf(c.x, c.x, fmaf(c.y, c.y, fmaf(c.z, c.z, c.w * c.w)));
}

// ---------------- precompute: 4 threads per point, LDS-staged weights ------------
__global__ __launch_bounds__(256) void gn_pre(
    const float* __restrict__ x,
    const float* __restrict__ Wf, const float* __restrict__ bf,
    const float* __restrict__ Ws, const float* __restrict__ bs,
    float* __restrict__ coords4, float* __restrict__ feats)
{
    __shared__ __align__(16) float sW[FIN * WCOLS];
    __shared__ float sB[WCOLS];

    int t = threadIdx.x;
    for (int idx = t; idx < FIN * WCOLS; idx += 256) {
        int i = idx >> 5, c = idx & 31;
        float v = 0.f;
        if (c < PP) v = Wf[i * PP + c];
        else if (c >= 24 && c < 28) v = Ws[i * 4 + (c - 24)];
        sW[idx] = v;
    }
    if (t < WCOLS) {
        float v = 0.f;
        if (t < PP) v = bf[t];
        else if (t >= 24 && t < 28) v = bs[t - 24];
        sB[t] = v;
    }
    __syncthreads();

    int gid = blockIdx.x * 256 + t;
    int p = gid >> 2;          // point
    int h = gid & 3;           // column strip
    int c0 = h * 8;

    const float4* xr4 = (const float4*)(x + (size_t)p * FIN);
    float acc[8];
    #pragma unroll
    for (int k = 0; k < 8; ++k) acc[k] = sB[c0 + k];

    #pragma unroll
    for (int i = 0; i < 8; ++i) {
        float4 xt = xr4[i];
        const float* w0 = sW + (4 * i + 0) * WCOLS + c0;
        const float* w1 = sW + (4 * i + 1) * WCOLS + c0;
        const float* w2 = sW + (4 * i + 2) * WCOLS + c0;
        const float* w3 = sW + (4 * i + 3) * WCOLS + c0;
        #pragma unroll
        for (int k = 0; k < 8; ++k) acc[k] = fmaf(xt.x, w0[k], acc[k]);
        #pragma unroll
        for (int k = 0; k < 8; ++k) acc[k] = fmaf(xt.y, w1[k], acc[k]);
        #pragma unroll
        for (int k = 0; k < 8; ++k) acc[k] = fmaf(xt.z, w2[k], acc[k]);
        #pragma unroll
        for (int k = 0; k < 8; ++k) acc[k] = fmaf(xt.w, w3[k], acc[k]);
    }

    if (h < 3) {
        float4* fw = (float4*)(feats + (size_t)p * PPAD + c0);
        fw[0] = make_float4(acc[0], acc[1], acc[2], acc[3]);
        fw[1] = make_float4(acc[4], acc[5], acc[6], acc[7]);   // h=2: cols 22,23 exact 0
    } else {
        ((float4*)coords4)[p] = make_float4(acc[0], acc[1], acc[2], acc[3]);
    }
}

// ---- fallback-only helpers (degenerate C > CAP path) ----------------------------
__device__ __forceinline__ void sort64_pair(float& v, int& m, int lane) {
    #pragma unroll
    for (int k = 2; k <= 64; k <<= 1) {
        #pragma unroll
        for (int j = k >> 1; j >= 1; j >>= 1) {
            float ov = __shfl_xor(v, j);
            int   om = __shfl_xor(m, j);
            bool keepMin = (((lane & j) == 0) == ((lane & k) == 0));
            bool less = (ov < v) || (ov == v && om < m);
            bool take = (less == keepMin);
            v = take ? ov : v;
            m = take ? om : m;
        }
    }
}
__device__ __forceinline__ void merge64(float& Lv, int& Lm, float cv, int cm, int lane) {
    float rv = __shfl_xor(cv, 63);
    int   rm = __shfl_xor(cm, 63);
    bool less = (rv < Lv) || (rv == Lv && rm < Lm);
    if (less) { Lv = rv; Lm = rm; }
    #pragma unroll
    for (int j = 32; j >= 1; j >>= 1) {
        float ov = __shfl_xor(Lv, j);
        int   om = __shfl_xor(Lm, j);
        bool lower = ((lane & j) == 0);
        bool l2 = (ov < Lv) || (ov == Lv && om < Lm);
        bool take = (l2 == lower);
        Lv = take ? ov : Lv;
        Lm = take ? om : Lm;
    }
}

// ------- round-8 full tail (used only on the rare C > CAP fallback path) ---------
__device__ __forceinline__ float tail_select(
    int lane, int b, int nj, int C,
    const unsigned short* __restrict__ selq,
    const float4* __restrict__ c4,
    const float* __restrict__ feats,
    float* __restrict__ fstage)
{
    const float INF = __builtin_inff();
    float4 cqj = c4[nj];
    float sqnj = sq4(cqj);

    if (C <= CAP) {
        unsigned kd0 = 0xFFFFFFFFu, ki0 = 0xFFFFFFFFu; float dv0 = 0.f;
        if (lane < C) {
            unsigned idx = (unsigned)selq[lane];
            float4 cm = c4[idx];
            float s2 = sq4(cm);
            float dt = fmaf(cqj.x, cm.x, fmaf(cqj.y, cm.y, fmaf(cqj.z, cm.z, cqj.w * cm.w)));
            float d  = fmaxf(fmaf(-2.f, dt, s2 + sqnj), 0.f);
            dv0 = d; kd0 = __float_as_uint(d); ki0 = idx;
        }
        unsigned kd1 = 0xFFFFFFFFu, ki1 = 0xFFFFFFFFu; float dv1 = 0.f;
        if (64 + lane < C) {
            unsigned idx = (unsigned)selq[64 + lane];
            float4 cm = c4[idx];
            float s2 = sq4(cm);
            float dt = fmaf(cqj.x, cm.x, fmaf(cqj.y, cm.y, fmaf(cqj.z, cm.z, cqj.w * cm.w)));
            float d  = fmaxf(fmaf(-2.f, dt, s2 + sqnj), 0.f);
            dv1 = d; kd1 = __float_as_uint(d); ki1 = idx;
        }
        unsigned D = 0;
        for (int bit = 30; bit >= 0; --bit) {
            unsigned t = D | (1u << bit);
            int c = (int)__popcll(__ballot(kd0 < t))
                  + (int)__popcll(__ballot(kd1 < t));
            if (c < KSEL) D = t;
        }
        int cless  = (int)__popcll(__ballot(kd0 < D))
                   + (int)__popcll(__ballot(kd1 < D));
        int tiecnt = (int)__popcll(__ballot(kd0 == D))
                   + (int)__popcll(__ballot(kd1 == D));
        int tneed = KSEL - cless;
        unsigned TI = 0xFFFFFFFFu;
        if (tiecnt > tneed) {
            unsigned pi = 0;
            for (int bit = 11; bit >= 0; --bit) {
                unsigned t = pi | (1u << bit);
                int c = (int)__popcll(__ballot((kd0 == D) && (ki0 < t)))
                      + (int)__popcll(__ballot((kd1 == D) && (ki1 < t)));
                if (c < tneed) pi = t;
            }
            TI = pi;
        }
        bool take0 = (kd0 < D) || ((kd0 == D) && (ki0 <= TI));
        bool take1 = (kd1 < D) || ((kd1 == D) && (ki1 <= TI));
        unsigned long long tb0 = __ballot(take0);
        unsigned long long tb1 = __ballot(take1);
        unsigned base1 = (unsigned)__popcll(tb0);
        if (take0) {
            unsigned slot = (unsigned)lane_prefix(tb0);
            float wgt = __expf(-10.f * dv0);
            const float4* fr = (const float4*)(feats + ((size_t)b * NN + ki0) * PPAD);
            float4 f0 = fr[0], f1 = fr[1], f2 = fr[2], f3 = fr[3], f4 = fr[4], f5 = fr[5];
            float4* row = (float4*)(fstage + slot * PPAD);
            row[0] = make_float4(f0.x * wgt, f0.y * wgt, f0.z * wgt, f0.w * wgt);
            row[1] = make_float4(f1.x * wgt, f1.y * wgt, f1.z * wgt, f1.w * wgt);
            row[2] = make_float4(f2.x * wgt, f2.y * wgt, f2.z * wgt, f2.w * wgt);
            row[3] = make_float4(f3.x * wgt, f3.y * wgt, f3.z * wgt, f3.w * wgt);
            row[4] = make_float4(f4.x * wgt, f4.y * wgt, f4.z * wgt, f4.w * wgt);
            row[5] = make_float4(f5.x * wgt, f5.y * wgt, f5.z * wgt, f5.w * wgt);
        }
        if (take1) {
            unsigned slot = base1 + (unsigned)lane_prefix(tb1);
            float wgt = __expf(-10.f * dv1);
            const float4* fr = (const float4*)(feats + ((size_t)b * NN + ki1) * PPAD);
            float4 f0 = fr[0], f1 = fr[1], f2 = fr[2], f3 = fr[3], f4 = fr[4], f5 = fr[5];
            float4* row = (float4*)(fstage + slot * PPAD);
            row[0] = make_float4(f0.x * wgt, f0.y * wgt, f0.z * wgt, f0.w * wgt);
            row[1] = make_float4(f1.x * wgt, f1.y * wgt, f1.z * wgt, f1.w * wgt);
            row[2] = make_float4(f2.x * wgt, f2.y * wgt, f2.z * wgt, f2.w * wgt);
            row[3] = make_float4(f3.x * wgt, f3.y * wgt, f3.z * wgt, f3.w * wgt);
            row[4] = make_float4(f4.x * wgt, f4.y * wgt, f4.z * wgt, f4.w * wgt);
            row[5] = make_float4(f5.x * wgt, f5.y * wgt, f5.z * wgt, f5.w * wgt);
        }
    } else {
        float Lv = INF; int Lm = 0x7FFFFFFF;
        for (int c = 0; c < 64; ++c) {
            int m = c * 64 + lane;
            float4 cm = c4[m];
            float s2 = sq4(cm);
            float dt = fmaf(cqj.x, cm.x, fmaf(cqj.y, cm.y, fmaf(cqj.z, cm.z, cqj.w * cm.w)));
            float v  = fmaxf(fmaf(-2.f, dt, s2 + sqnj), 0.f);
            if (m == nj) v = INF;
            sort64_pair(v, m, lane);
            if (c == 0) { Lv = v; Lm = m; }
            else        merge64(Lv, Lm, v, m, lane);
        }
        if (lane < KSEL) {
            float wgt = __expf(-10.f * Lv);
            const float4* fr = (const float4*)(feats + ((size_t)b * NN + Lm) * PPAD);
            float4 f0 = fr[0], f1 = fr[1], f2 = fr[2], f3 = fr[3], f4 = fr[4], f5 = fr[5];
            float4* row = (float4*)(fstage + lane * PPAD);
            row[0] = make_float4(f0.x * wgt, f0.y * wgt, f0.z * wgt, f0.w * wgt);
            row[1] = make_float4(f1.x * wgt, f1.y * wgt, f1.z * wgt, f1.w * wgt);
            row[2] = make_float4(f2.x * wgt, f2.y * wgt, f2.z * wgt, f2.w * wgt);
            row[3] = make_float4(f3.x * wgt, f3.y * wgt, f3.z * wgt, f3.w * wgt);
            row[4] = make_float4(f4.x * wgt, f4.y * wgt, f4.z * wgt, f4.w * wgt);
            row[5] = make_float4(f5.x * wgt, f5.y * wgt, f5.z * wgt, f5.w * wgt);
        }
    }
    WSYNC();

    float aggv = 0.f;
    if (lane < 2 * PP) {
        int c = (lane < PP) ? lane : lane - PP;
        float mx = -INF, sm = 0.f;
        for (int k = 0; k < KSEL; ++k) {
            float v = fstage[k * PPAD + c];
            mx = fmaxf(mx, v);
            sm += v;
        }
        aggv = (lane < PP) ? mx : sm * (1.f / (float)KSEL);
    }
    WSYNC();
    return aggv;
}

// ------- fast-path pieces: gather / emit-list / materialize+aggregate ------------
__device__ __forceinline__ void gather_slot(
    int slotIdx, int C, const unsigned short* __restrict__ selq,
    const float4* __restrict__ c4, float4 cqj, float sqnj,
    unsigned& kd, unsigned& ki)
{
    kd = 0xFFFFFFFFu; ki = 0xFFFFFFFFu;
    if (slotIdx < C) {
        unsigned idx = (unsigned)selq[slotIdx];
        float4 cm = c4[idx];
        float s2 = sq4(cm);
        float dt = fmaf(cqj.x, cm.x, fmaf(cqj.y, cm.y, fmaf(cqj.z, cm.z, cqj.w * cm.w)));
        float d  = fmaxf(fmaf(-2.f, dt, s2 + sqnj), 0.f);
        kd = __float_as_uint(d); ki = idx;
    }
}

// ties + takes + write compact (d, ki) list (identical slot order to round 8)
__device__ __forceinline__ void emit_list(
    unsigned kd0, unsigned ki0, unsigned kd1, unsigned ki1, unsigned D,
    float2* __restrict__ stg)
{
    int cless  = (int)__popcll(__ballot(kd0 < D))
               + (int)__popcll(__ballot(kd1 < D));
    int tiecnt = (int)__popcll(__ballot(kd0 == D))
               + (int)__popcll(__ballot(kd1 == D));
    int tneed = KSEL - cless;
    unsigned TI = 0xFFFFFFFFu;
    if (tiecnt > tneed) {                // rare: resolve ties by lowest index
        unsigned pi = 0;
        for (int bit = 11; bit >= 0; --bit) {
            unsigned t = pi | (1u << bit);
            int c = (int)__popcll(__ballot((kd0 == D) && (ki0 < t)))
                  + (int)__popcll(__ballot((kd1 == D) && (ki1 < t)));
            if (c < tneed) pi = t;
        }
        TI = pi;
    }
    bool take0 = (kd0 < D) || ((kd0 == D) && (ki0 <= TI));
    bool take1 = (kd1 < D) || ((kd1 == D) && (ki1 <= TI));
    unsigned long long tb0 = __ballot(take0);
    unsigned long long tb1 = __ballot(take1);
    unsigned base1 = (unsigned)__popcll(tb0);
    if (take0) {
        unsigned slot = (unsigned)lane_prefix(tb0);
        stg[slot] = make_float2(__uint_as_float(kd0), __uint_as_float(ki0));
    }
    if (take1) {
        unsigned slot = base1 + (unsigned)lane_prefix(tb1);
        stg[slot] = make_float2(__uint_as_float(kd1), __uint_as_float(ki1));
    }
}

// 39-lane materialize from list into fstage, then packed aggregate (round-8 form)
__device__ __forceinline__ float mat_agg(
    int lane, int b, const float2* __restrict__ stg,
    const float* __restrict__ feats, float* __restrict__ fstage)
{
    const float INF = __builtin_inff();
    if (lane < KSEL) {
        float2 e = stg[lane];
        float d = e.x;
        unsigned ki = __float_as_uint(e.y);
        float wgt = __expf(-10.f * d);
        const float4* fr = (const float4*)(feats + ((size_t)b * NN + ki) * PPAD);
        float4 f0 = fr[0], f1 = fr[1], f2 = fr[2], f3 = fr[3], f4 = fr[4], f5 = fr[5];
        float4* row = (float4*)(fstage + lane * PPAD);
        row[0] = make_float4(f0.x * wgt, f0.y * wgt, f0.z * wgt, f0.w * wgt);
        row[1] = make_float4(f1.x * wgt, f1.y * wgt, f1.z * wgt, f1.w * wgt);
        row[2] = make_float4(f2.x * wgt, f2.y * wgt, f2.z * wgt, f2.w * wgt);
        row[3] = make_float4(f3.x * wgt, f3.y * wgt, f3.z * wgt, f3.w * wgt);
        row[4] = make_float4(f4.x * wgt, f4.y * wgt, f4.z * wgt, f4.w * wgt);
        row[5] = make_float4(f5.x * wgt, f5.y * wgt, f5.z * wgt, f5.w * wgt);
    }
    WSYNC();

    float aggv = 0.f;
    if (lane < 2 * PP) {
        int c = (lane < PP) ? lane : lane - PP;
        float mx = -INF, sm = 0.f;
        for (int k = 0; k < KSEL; ++k) {
            float v = fstage[k * PPAD + c];
            mx = fmaxf(mx, v);
            sm += v;
        }
        aggv = (lane < PP) ? mx : sm * (1.f / (float)KSEL);
    }
    WSYNC();
    return aggv;
}

// ---------------- main: one wave per FOUR queries, pair-fused tails --------------
__global__ __launch_bounds__(WPB * 64, 8) void gn_main(
    const float* __restrict__ x,
    const float* __restrict__ Wo, const float* __restrict__ bo,
    const float* __restrict__ coords4,
    const float* __restrict__ feats,
    float* __restrict__ out)
{
    __shared__ unsigned short sel_s[WPB * QW * CAP];     // candidate indices
    __shared__ float fstage_s[WPB * KSEL * PPAD];
    __shared__ unsigned cnt_s[WPB * QW];                 // compact slot counters
    __shared__ float2 stg_s[WPB * 2 * KSEL];             // (d, ki) lists, 2 per wave

    const float INF = __builtin_inff();
    const int wv    = threadIdx.x >> 6;
    const int lane  = threadIdx.x & 63;
    const int qbase = (blockIdx.x * WPB + wv) * QW;      // 4 queries, same batch
    const int b     = qbase >> 12;
    const int n0    = qbase & (NN - 1);
    unsigned short* selp = sel_s + wv * QW * CAP;
    unsigned* cnt = cnt_s + wv * QW;
    float* fstage = fstage_s + wv * (KSEL * PPAD);
    float2* stgA = stg_s + wv * 2 * KSEL;
    float2* stgB = stgA + KSEL;

    const float4* c4 = ((const float4*)coords4) + (size_t)b * NN;

    if (lane < QW) cnt[lane] = 0;

    // hoisted -2*q components (query coords NOT kept live -- tails reload them).
    // e = s2 - 2*dot with s2 recomputed (bit-identical chain). Selection in
    // e-domain; widened bound keeps an exact superset; tails re-rank exactly.
    float4 cq0 = c4[n0 + 0], cq1 = c4[n0 + 1], cq2 = c4[n0 + 2], cq3 = c4[n0 + 3];
    float m2x0 = -2.f * cq0.x, m2y0 = -2.f * cq0.y, m2z0 = -2.f * cq0.z, m2w0 = -2.f * cq0.w;
    float m2x1 = -2.f * cq1.x, m2y1 = -2.f * cq1.y, m2z1 = -2.f * cq1.z, m2w1 = -2.f * cq1.w;
    float m2x2 = -2.f * cq2.x, m2y2 = -2.f * cq2.y, m2z2 = -2.f * cq2.z, m2w2 = -2.f * cq2.w;
    float m2x3 = -2.f * cq3.x, m2y3 = -2.f * cq3.y, m2z3 = -2.f * cq3.z, m2w3 = -2.f * cq3.w;

    // ---- pass 1: per-query running min of e (self included) ----
    float km0 = INF, km1 = INF, km2 = INF, km3 = INF;
    #pragma unroll 4
    for (int i = 0; i < 64; ++i) {
        float4 cm = c4[i * 64 + lane];
        float s2  = sq4(cm);
        float e0 = fmaf(m2x0, cm.x, fmaf(m2y0, cm.y, fmaf(m2z0, cm.z, fmaf(m2w0, cm.w, s2))));
        float e1 = fmaf(m2x1, cm.x, fmaf(m2y1, cm.y, fmaf(m2z1, cm.z, fmaf(m2w1, cm.w, s2))));
        float e2 = fmaf(m2x2, cm.x, fmaf(m2y2, cm.y, fmaf(m2z2, cm.z, fmaf(m2w2, cm.w, s2))));
        float e3 = fmaf(m2x3, cm.x, fmaf(m2y3, cm.y, fmaf(m2z3, cm.z, fmaf(m2w3, cm.w, s2))));
        km0 = fminf(km0, e0);
        km1 = fminf(km1, e1);
        km2 = fminf(km2, e2);
        km3 = fminf(km3, e3);
    }
    unsigned kb0 = ford(km0), kb1 = ford(km1), kb2 = ford(km2), kb3 = ford(km3);

    // ---- bound: 40th-smallest lane-min key, TRUNCATED radix (bits 31..15),
    //      widen low 15 bits -> guaranteed >= exact 40th e. Exact superset.
    unsigned ub0 = 0, ub1 = 0, ub2 = 0, ub3 = 0;
    for (int bit = 31; bit >= 15; --bit) {
        unsigned msk = 1u << bit;
        unsigned t0 = ub0 | msk, t1 = ub1 | msk, t2 = ub2 | msk, t3 = ub3 | msk;
        if ((int)__popcll(__ballot(kb0 < t0)) < KSEL + 1) ub0 = t0;
        if ((int)__popcll(__ballot(kb1 < t1)) < KSEL + 1) ub1 = t1;
        if ((int)__popcll(__ballot(kb2 < t2)) < KSEL + 1) ub2 = t2;
        if ((int)__popcll(__ballot(kb3 < t3)) < KSEL + 1) ub3 = t3;
    }
    float UBe0 = funord(ub0 | 0x7FFFu);
    float UBe1 = funord(ub1 | 0x7FFFu);
    float UBe2 = funord(ub2 | 0x7FFFu);
    float UBe3 = funord(ub3 | 0x7FFFu);

    // selves all sit in iteration iSelf at lanes l0..l0+3 (n0 % 4 == 0)
    const int iSelf = n0 >> 6;
    const int l0    = n0 & 63;
    WSYNC();                                   // cnt init visible (wave-local)

    // ---- compact pass: LDS atomic slot assignment (VALU -> LDS-pipe trade) ----
    #pragma unroll 4
    for (int i = 0; i < 64; ++i) {
        int m = i * 64 + lane;
        float4 cm = c4[m];
        float s2  = sq4(cm);
        float e0 = fmaf(m2x0, cm.x, fmaf(m2y0, cm.y, fmaf(m2z0, cm.z, fmaf(m2w0, cm.w, s2))));
        float e1 = fmaf(m2x1, cm.x, fmaf(m2y1, cm.y, fmaf(m2z1, cm.z, fmaf(m2w1, cm.w, s2))));
        float e2 = fmaf(m2x2, cm.x, fmaf(m2y2, cm.y, fmaf(m2z2, cm.z, fmaf(m2w2, cm.w, s2))));
        float e3 = fmaf(m2x3, cm.x, fmaf(m2y3, cm.y, fmaf(m2z3, cm.z, fmaf(m2w3, cm.w, s2))));
        bool t0 = (e0 <= UBe0);
        bool t1 = (e1 <= UBe1);
        bool t2 = (e2 <= UBe2);
        bool t3 = (e3 <= UBe3);
        if (i == iSelf) {                      // wave-uniform, 1 of 64 iters
            t0 = t0 && (lane != l0 + 0);
            t1 = t1 && (lane != l0 + 1);
            t2 = t2 && (lane != l0 + 2);
            t3 = t3 && (lane != l0 + 3);
        }
        if (t0) {
            unsigned s = atomicAdd(&cnt[0], 1u) & (CAP - 1);
            selp[0 * CAP + s] = (unsigned short)m;
        }
        if (t1) {
            unsigned s = atomicAdd(&cnt[1], 1u) & (CAP - 1);
            selp[1 * CAP + s] = (unsigned short)m;
        }
        if (t2) {
            unsigned s = atomicAdd(&cnt[2], 1u) & (CAP - 1);
            selp[2 * CAP + s] = (unsigned short)m;
        }
        if (t3) {
            unsigned s = atomicAdd(&cnt[3], 1u) & (CAP - 1);
            selp[3 * CAP + s] = (unsigned short)m;
        }
    }
    WSYNC();
    int cc0 = (int)cnt[0];
    int cc1 = (int)cnt[1];
    int cc2 = (int)cnt[2];
    int cc3 = (int)cnt[3];
    WSYNC();

    float agg0, agg1, agg2, agg3;

    // ---- pair (0,1): gathers together, interleaved D-radix, indirect staging ----
    if (cc0 <= CAP && cc1 <= CAP) {
        float4 cqa = c4[n0 + 0]; float sqa = sq4(cqa);
        float4 cqb = c4[n0 + 1]; float sqb = sq4(cqb);
        unsigned kA0, iA0, kA1, iA1, kB0, iB0, kB1, iB1;
        gather_slot(lane,      cc0, selp + 0 * CAP, c4, cqa, sqa, kA0, iA0);
        gather_slot(64 + lane, cc0, selp + 0 * CAP, c4, cqa, sqa, kA1, iA1);
        gather_slot(lane,      cc1, selp + 1 * CAP, c4, cqb, sqb, kB0, iB0);
        gather_slot(64 + lane, cc1, selp + 1 * CAP, c4, cqb, sqb, kB1, iB1);
        unsigned DA = 0, DB = 0;
        for (int bit = 30; bit >= 0; --bit) {
            unsigned mA = DA | (1u << bit), mB = DB | (1u << bit);
            int ca = (int)__popcll(__ballot(kA0 < mA)) + (int)__popcll(__ballot(kA1 < mA));
            int cb = (int)__popcll(__ballot(kB0 < mB)) + (int)__popcll(__ballot(kB1 < mB));
            if (ca < KSEL) DA = mA;
            if (cb < KSEL) DB = mB;
        }
        emit_list(kA0, iA0, kA1, iA1, DA, stgA);
        emit_list(kB0, iB0, kB1, iB1, DB, stgB);
        WSYNC();
        agg0 = mat_agg(lane, b, stgA, feats, fstage);
        agg1 = mat_agg(lane, b, stgB, feats, fstage);
    } else {
        agg0 = tail_select(lane, b, n0 + 0, cc0, selp + 0 * CAP, c4, feats, fstage);
        agg1 = tail_select(lane, b, n0 + 1, cc1, selp + 1 * CAP, c4, feats, fstage);
    }

    // ---- pair (2,3) ----
    if (cc2 <= CAP && cc3 <= CAP) {
        float4 cqa = c4[n0 + 2]; float sqa = sq4(cqa);
        float4 cqb = c4[n0 + 3]; float sqb = sq4(cqb);
        unsigned kA0, iA0, kA1, iA1, kB0, iB0, kB1, iB1;
        gather_slot(lane,      cc2, selp + 2 * CAP, c4, cqa, sqa, kA0, iA0);
        gather_slot(64 + lane, cc2, selp + 2 * CAP, c4, cqa, sqa, kA1, iA1);
        gather_slot(lane,      cc3, selp + 3 * CAP, c4, cqb, sqb, kB0, iB0);
        gather_slot(64 + lane, cc3, selp + 3 * CAP, c4, cqb, sqb, kB1, iB1);
        unsigned DA = 0, DB = 0;
        for (int bit = 30; bit >= 0; --bit) {
            unsigned mA = DA | (1u << bit), mB = DB | (1u << bit);
            int ca = (int)__popcll(__ballot(kA0 < mA)) + (int)__popcll(__ballot(kA1 < mA));
            int cb = (int)__popcll(__ballot(kB0 < mB)) + (int)__popcll(__ballot(kB1 < mB));
            if (ca < KSEL) DA = mA;
            if (cb < KSEL) DB = mB;
        }
        emit_list(kA0, iA0, kA1, iA1, DA, stgA);
        emit_list(kB0, iB0, kB1, iB1, DB, stgB);
        WSYNC();
        agg2 = mat_agg(lane, b, stgA, feats, fstage);
        agg3 = mat_agg(lane, b, stgB, feats, fstage);
    } else {
        agg2 = tail_select(lane, b, n0 + 2, cc2, selp + 2 * CAP, c4, feats, fstage);
        agg3 = tail_select(lane, b, n0 + 3, cc3, selp + 3 * CAP, c4, feats, fstage);
    }

    // ---- FUSED epilogue: Wo loaded ONCE for all 4 queries; x via scalar loads ----
    const int qbU = __builtin_amdgcn_readfirstlane(qbase);
    const float* xu = x + (size_t)qbU * FIN;             // uniform -> SMEM loads
    if (lane < FOUT) {
        const float* woL = Wo + lane;
        float bb = bo[lane];
        float a00 = bb, a01 = 0.f, a02 = 0.f, a03 = 0.f;
        float a10 = bb, a11 = 0.f, a12 = 0.f, a13 = 0.f;
        float a20 = bb, a21 = 0.f, a22 = 0.f, a23 = 0.f;
        float a30 = bb, a31 = 0.f, a32 = 0.f, a33 = 0.f;
        #pragma unroll
        for (int f = 0; f < FIN; f += 4) {
            float w0 = woL[(f + 0) * FOUT];
            float w1 = woL[(f + 1) * FOUT];
            float w2 = woL[(f + 2) * FOUT];
            float w3 = woL[(f + 3) * FOUT];
            a00 = fmaf(xu[0 * FIN + f + 0], w0, a00);
            a01 = fmaf(xu[0 * FIN + f + 1], w1, a01);
            a02 = fmaf(xu[0 * FIN + f + 2], w2, a02);
            a03 = fmaf(xu[0 * FIN + f + 3], w3, a03);
            a10 = fmaf(xu[1 * FIN + f + 0], w0, a10);
            a11 = fmaf(xu[1 * FIN + f + 1], w1, a11);
            a12 = fmaf(xu[1 * FIN + f + 2], w2, a12);
            a13 = fmaf(xu[1 * FIN + f + 3], w3, a13);
            a20 = fmaf(xu[2 * FIN + f + 0], w0, a20);
            a21 = fmaf(xu[2 * FIN + f + 1], w1, a21);
            a22 = fmaf(xu[2 * FIN + f + 2], w2, a22);
            a23 = fmaf(xu[2 * FIN + f + 3], w3, a23);
            a30 = fmaf(xu[3 * FIN + f + 0], w0, a30);
            a31 = fmaf(xu[3 * FIN + f + 1], w1, a31);
            a32 = fmaf(xu[3 * FIN + f + 2], w2, a32);
            a33 = fmaf(xu[3 * FIN + f + 3], w3, a33);
        }
        #pragma unroll
        for (int g = 0; g < 2 * PP; g += 4) {
            float w0 = woL[(FIN + g + 0) * FOUT];
            float w1 = woL[(FIN + g + 1) * FOUT];
            float w2 = woL[(FIN + g + 2) * FOUT];
            float w3 = woL[(FIN + g + 3) * FOUT];
            a00 = fmaf(lane_bcast(agg0, g + 0), w0, a00);
            a01 = fmaf(lane_bcast(agg0, g + 1), w1, a01);
            a02 = fmaf(lane_bcast(agg0, g + 2), w2, a02);
            a03 = fmaf(lane_bcast(agg0, g + 3), w3, a03);
            a10 = fmaf(lane_bcast(agg1, g + 0), w0, a10);
            a11 = fmaf(lane_bcast(agg1, g + 1), w1, a11);
            a12 = fmaf(lane_bcast(agg1, g + 2), w2, a12);
            a13 = fmaf(lane_bcast(agg1, g + 3), w3, a13);
            a20 = fmaf(lane_bcast(agg2, g + 0), w0, a20);
            a21 = fmaf(lane_bcast(agg2, g + 1), w1, a21);
            a22 = fmaf(lane_bcast(agg2, g + 2), w2, a22);
            a23 = fmaf(lane_bcast(agg2, g + 3), w3, a23);
            a30 = fmaf(lane_bcast(agg3, g + 0), w0, a30);
            a31 = fmaf(lane_bcast(agg3, g + 1), w1, a31);
            a32 = fmaf(lane_bcast(agg3, g + 2), w2, a32);
            a33 = fmaf(lane_bcast(agg3, g + 3), w3, a33);
        }
        float ac0 = (a00 + a01) + (a02 + a03);
        float ac1 = (a10 + a11) + (a12 + a13);
        float ac2 = (a20 + a21) + (a22 + a23);
        float ac3 = (a30 + a31) + (a32 + a33);
        float e0 = __expf(2.f * ac0);
        float e1 = __expf(2.f * ac1);
        float e2 = __expf(2.f * ac2);
        float e3 = __expf(2.f * ac3);
        float r0 = __builtin_amdgcn_rcpf(e0 + 1.f);
        float r1 = __builtin_amdgcn_rcpf(e1 + 1.f);
        float r2 = __builtin_amdgcn_rcpf(e2 + 1.f);
        float r3 = __builtin_amdgcn_rcpf(e3 + 1.f);
        out[(size_t)(qbU + 0) * FOUT + lane] = fmaf(-2.f, r0, 1.f);
        out[(size_t)(qbU + 1) * FOUT + lane] = fmaf(-2.f, r1, 1.f);
        out[(size_t)(qbU + 2) * FOUT + lane] = fmaf(-2.f, r2, 1.f);
        out[(size_t)(qbU + 3) * FOUT + lane] = fmaf(-2.f, r3, 1.f);
    }
}

extern "C" void kernel_launch(void* const* d_in, const int* in_sizes, int n_in,
                              void* d_out, int out_size, void* d_ws, size_t ws_size,
                              hipStream_t stream) {
    const float* x  = (const float*)d_in[0];
    const float* Wf = (const float*)d_in[1];
    const float* bf = (const float*)d_in[2];
    const float* Ws = (const float*)d_in[3];
    const float* bs = (const float*)d_in[4];
    const float* Wo = (const float*)d_in[5];
    const float* bo = (const float*)d_in[6];
    float* outp = (float*)d_out;

    float* ws      = (float*)d_ws;
    float* coords4 = ws;                      // 32768*4  = 131072 floats
    float* feats   = ws + 131072;             // 32768*24 = 786432 floats

    gn_pre<<<(32768 * 4) / 256, 256, 0, stream>>>(x, Wf, bf, Ws, bs, coords4, feats);
    gn_main<<<32768 / (WPB * QW), WPB * 64, 0, stream>>>(x, Wo, bo, coords4, feats, outp);
}

// Round 11
// 147.587 us; speedup vs baseline: 1.1478x; 1.1478x over previous
//
#include <hip/hip_runtime.h>
#include <cmath>

#define NN    4096
#define FIN   32
#define KSEL  39      // neighbors kept (top-40 minus self)
#define PP    22
#define PPAD  24
#define FOUT  48
#define WPB   2       // waves per block
#define QW    4       // queries per wave
#define CAP   128     // candidate cap per query (fallback if exceeded)
#define WCOLS 32      // combined weight columns: [Wf(22) | pad(2) | Ws(4) | pad(4)]

#define WSYNC() asm volatile("s_waitcnt lgkmcnt(0)" ::: "memory")

__device__ __forceinline__ int lane_prefix(unsigned long long m) {
    return __builtin_amdgcn_mbcnt_hi((unsigned)(m >> 32),
           __builtin_amdgcn_mbcnt_lo((unsigned)m, 0));
}
// order-preserving float->uint map (total order, handles negatives)
__device__ __forceinline__ unsigned ford(float f) {
    int u = __float_as_int(f);
    return (u >= 0) ? ((unsigned)u | 0x80000000u) : ~(unsigned)u;
}
__device__ __forceinline__ float funord(unsigned k) {
    unsigned v = (k & 0x80000000u) ? (k & 0x7FFFFFFFu) : ~k;
    return __uint_as_float(v);
}
// broadcast lane l's value (l must be wave-uniform; here a literal)
__device__ __forceinline__ float lane_bcast(float v, int l) {
    return __uint_as_float((unsigned)__builtin_amdgcn_readlane((int)__float_as_uint(v), l));
}
// |c|^2 with the EXACT gn_pre FMA order (bit-identical everywhere)
__device__ __forceinline__ float sq4(float4 c) {
    return fmaf(c.x, c.x, fmaf(c.y, c.y, fmaf(c.z, c.z, c.w * c.w)));
}

// ---------------- precompute: 4 threads per point, LDS-staged weights ------------
__global__ __launch_bounds__(256) void gn_pre(
    const float* __restrict__ x,
    const float* __restrict__ Wf, const float* __restrict__ bf,
    const float* __restrict__ Ws, const float* __restrict__ bs,
    float* __restrict__ coords4, float* __restrict__ feats)
{
    __shared__ __align__(16) float sW[FIN * WCOLS];
    __shared__ float sB[WCOLS];

    int t = threadIdx.x;
    for (int idx = t; idx < FIN * WCOLS; idx += 256) {
        int i = idx >> 5, c = idx & 31;
        float v = 0.f;
        if (c < PP) v = Wf[i * PP + c];
        else if (c >= 24 && c < 28) v = Ws[i * 4 + (c - 24)];
        sW[idx] = v;
    }
    if (t < WCOLS) {
        float v = 0.f;
        if (t < PP) v = bf[t];
        else if (t >= 24 && t < 28) v = bs[t - 24];
        sB[t] = v;
    }
    __syncthreads();

    int gid = blockIdx.x * 256 + t;
    int p = gid >> 2;          // point
    int h = gid & 3;           // column strip
    int c0 = h * 8;

    const float4* xr4 = (const float4*)(x + (size_t)p * FIN);
    float acc[8];
    #pragma unroll
    for (int k = 0; k < 8; ++k) acc[k] = sB[c0 + k];

    #pragma unroll
    for (int i = 0; i < 8; ++i) {
        float4 xt = xr4[i];
        const float* w0 = sW + (4 * i + 0) * WCOLS + c0;
        const float* w1 = sW + (4 * i + 1) * WCOLS + c0;
        const float* w2 = sW + (4 * i + 2) * WCOLS + c0;
        const float* w3 = sW + (4 * i + 3) * WCOLS + c0;
        #pragma unroll
        for (int k = 0; k < 8; ++k) acc[k] = fmaf(xt.x, w0[k], acc[k]);
        #pragma unroll
        for (int k = 0; k < 8; ++k) acc[k] = fmaf(xt.y, w1[k], acc[k]);
        #pragma unroll
        for (int k = 0; k < 8; ++k) acc[k] = fmaf(xt.z, w2[k], acc[k]);
        #pragma unroll
        for (int k = 0; k < 8; ++k) acc[k] = fmaf(xt.w, w3[k], acc[k]);
    }

    if (h < 3) {
        float4* fw = (float4*)(feats + (size_t)p * PPAD + c0);
        fw[0] = make_float4(acc[0], acc[1], acc[2], acc[3]);
        fw[1] = make_float4(acc[4], acc[5], acc[6], acc[7]);   // h=2: cols 22,23 exact 0
    } else {
        ((float4*)coords4)[p] = make_float4(acc[0], acc[1], acc[2], acc[3]);
    }
}

// ---- fallback-only helpers (degenerate C > CAP path) ----------------------------
__device__ __forceinline__ void sort64_pair(float& v, int& m, int lane) {
    #pragma unroll
    for (int k = 2; k <= 64; k <<= 1) {
        #pragma unroll
        for (int j = k >> 1; j >= 1; j >>= 1) {
            float ov = __shfl_xor(v, j);
            int   om = __shfl_xor(m, j);
            bool keepMin = (((lane & j) == 0) == ((lane & k) == 0));
            bool less = (ov < v) || (ov == v && om < m);
            bool take = (less == keepMin);
            v = take ? ov : v;
            m = take ? om : m;
        }
    }
}
__device__ __forceinline__ void merge64(float& Lv, int& Lm, float cv, int cm, int lane) {
    float rv = __shfl_xor(cv, 63);
    int   rm = __shfl_xor(cm, 63);
    bool less = (rv < Lv) || (rv == Lv && rm < Lm);
    if (less) { Lv = rv; Lm = rm; }
    #pragma unroll
    for (int j = 32; j >= 1; j >>= 1) {
        float ov = __shfl_xor(Lv, j);
        int   om = __shfl_xor(Lm, j);
        bool lower = ((lane & j) == 0);
        bool l2 = (ov < Lv) || (ov == Lv && om < Lm);
        bool take = (l2 == lower);
        Lv = take ? ov : Lv;
        Lm = take ? om : Lm;
    }
}

// ------- per-query selection + staging + packed aggregate (NO epilogue here) -----
// Selection math bit-identical to the verified kernel; s2 recomputed (same bits).
// Returns packed agg: lane c<22 -> max_c ; lane 22+c -> mean_c ; others 0.
__device__ __forceinline__ float tail_select(
    int lane, int b, int nj, int C,
    const unsigned short* __restrict__ selq,
    const float4* __restrict__ c4,
    const float* __restrict__ feats,
    float* __restrict__ fstage)
{
    const float INF = __builtin_inff();
    float4 cqj = c4[nj];
    float sqnj = sq4(cqj);

    if (C <= CAP) {
        unsigned kd0 = 0xFFFFFFFFu, ki0 = 0xFFFFFFFFu; float dv0 = 0.f;
        if (lane < C) {
            unsigned idx = (unsigned)selq[lane];
            float4 cm = c4[idx];
            float s2 = sq4(cm);
            float dt = fmaf(cqj.x, cm.x, fmaf(cqj.y, cm.y, fmaf(cqj.z, cm.z, cqj.w * cm.w)));
            float d  = fmaxf(fmaf(-2.f, dt, s2 + sqnj), 0.f);
            dv0 = d; kd0 = __float_as_uint(d); ki0 = idx;
        }
        unsigned kd1 = 0xFFFFFFFFu, ki1 = 0xFFFFFFFFu; float dv1 = 0.f;
        if (64 + lane < C) {
            unsigned idx = (unsigned)selq[64 + lane];
            float4 cm = c4[idx];
            float s2 = sq4(cm);
            float dt = fmaf(cqj.x, cm.x, fmaf(cqj.y, cm.y, fmaf(cqj.z, cm.z, cqj.w * cm.w)));
            float d  = fmaxf(fmaf(-2.f, dt, s2 + sqnj), 0.f);
            dv1 = d; kd1 = __float_as_uint(d); ki1 = idx;
        }
        // D = exact 39th-smallest clamped d2 bits (must stay exact)
        unsigned D = 0;
        for (int bit = 30; bit >= 0; --bit) {
            unsigned t = D | (1u << bit);
            int c = (int)__popcll(__ballot(kd0 < t))
                  + (int)__popcll(__ballot(kd1 < t));
            if (c < KSEL) D = t;
        }
        int cless  = (int)__popcll(__ballot(kd0 < D))
                   + (int)__popcll(__ballot(kd1 < D));
        int tiecnt = (int)__popcll(__ballot(kd0 == D))
                   + (int)__popcll(__ballot(kd1 == D));
        int tneed = KSEL - cless;
        unsigned TI = 0xFFFFFFFFu;
        if (tiecnt > tneed) {            // rare: resolve ties by lowest index
            unsigned pi = 0;
            for (int bit = 11; bit >= 0; --bit) {
                unsigned t = pi | (1u << bit);
                int c = (int)__popcll(__ballot((kd0 == D) && (ki0 < t)))
                      + (int)__popcll(__ballot((kd1 == D) && (ki1 < t)));
                if (c < tneed) pi = t;
            }
            TI = pi;
        }
        // stage the exactly-39 selected neighbors (ballot/prefix slots, no atomics)
        bool take0 = (kd0 < D) || ((kd0 == D) && (ki0 <= TI));
        bool take1 = (kd1 < D) || ((kd1 == D) && (ki1 <= TI));
        unsigned long long tb0 = __ballot(take0);
        unsigned long long tb1 = __ballot(take1);
        unsigned base1 = (unsigned)__popcll(tb0);
        if (take0) {
            unsigned slot = (unsigned)lane_prefix(tb0);
            float wgt = __expf(-10.f * dv0);
            const float4* fr = (const float4*)(feats + ((size_t)b * NN + ki0) * PPAD);
            float4 f0 = fr[0], f1 = fr[1], f2 = fr[2], f3 = fr[3], f4 = fr[4], f5 = fr[5];
            float4* row = (float4*)(fstage + slot * PPAD);
            row[0] = make_float4(f0.x * wgt, f0.y * wgt, f0.z * wgt, f0.w * wgt);
            row[1] = make_float4(f1.x * wgt, f1.y * wgt, f1.z * wgt, f1.w * wgt);
            row[2] = make_float4(f2.x * wgt, f2.y * wgt, f2.z * wgt, f2.w * wgt);
            row[3] = make_float4(f3.x * wgt, f3.y * wgt, f3.z * wgt, f3.w * wgt);
            row[4] = make_float4(f4.x * wgt, f4.y * wgt, f4.z * wgt, f4.w * wgt);
            row[5] = make_float4(f5.x * wgt, f5.y * wgt, f5.z * wgt, f5.w * wgt);
        }
        if (take1) {
            unsigned slot = base1 + (unsigned)lane_prefix(tb1);
            float wgt = __expf(-10.f * dv1);
            const float4* fr = (const float4*)(feats + ((size_t)b * NN + ki1) * PPAD);
            float4 f0 = fr[0], f1 = fr[1], f2 = fr[2], f3 = fr[3], f4 = fr[4], f5 = fr[5];
            float4* row = (float4*)(fstage + slot * PPAD);
            row[0] = make_float4(f0.x * wgt, f0.y * wgt, f0.z * wgt, f0.w * wgt);
            row[1] = make_float4(f1.x * wgt, f1.y * wgt, f1.z * wgt, f1.w * wgt);
            row[2] = make_float4(f2.x * wgt, f2.y * wgt, f2.z * wgt, f2.w * wgt);
            row[3] = make_float4(f3.x * wgt, f3.y * wgt, f3.z * wgt, f3.w * wgt);
            row[4] = make_float4(f4.x * wgt, f4.y * wgt, f4.z * wgt, f4.w * wgt);
            row[5] = make_float4(f5.x * wgt, f5.y * wgt, f5.z * wgt, f5.w * wgt);
        }
    } else {
        // degenerate fallback: exact streaming top-64 over all 4096
        float Lv = INF; int Lm = 0x7FFFFFFF;
        for (int c = 0; c < 64; ++c) {
            int m = c * 64 + lane;
            float4 cm = c4[m];
            float s2 = sq4(cm);
            float dt = fmaf(cqj.x, cm.x, fmaf(cqj.y, cm.y, fmaf(cqj.z, cm.z, cqj.w * cm.w)));
            float v  = fmaxf(fmaf(-2.f, dt, s2 + sqnj), 0.f);
            if (m == nj) v = INF;
            sort64_pair(v, m, lane);
            if (c == 0) { Lv = v; Lm = m; }
            else        merge64(Lv, Lm, v, m, lane);
        }
        if (lane < KSEL) {
            float wgt = __expf(-10.f * Lv);
            const float4* fr = (const float4*)(feats + ((size_t)b * NN + Lm) * PPAD);
            float4 f0 = fr[0], f1 = fr[1], f2 = fr[2], f3 = fr[3], f4 = fr[4], f5 = fr[5];
            float4* row = (float4*)(fstage + lane * PPAD);
            row[0] = make_float4(f0.x * wgt, f0.y * wgt, f0.z * wgt, f0.w * wgt);
            row[1] = make_float4(f1.x * wgt, f1.y * wgt, f1.z * wgt, f1.w * wgt);
            row[2] = make_float4(f2.x * wgt, f2.y * wgt, f2.z * wgt, f2.w * wgt);
            row[3] = make_float4(f3.x * wgt, f3.y * wgt, f3.z * wgt, f3.w * wgt);
            row[4] = make_float4(f4.x * wgt, f4.y * wgt, f4.z * wgt, f4.w * wgt);
            row[5] = make_float4(f5.x * wgt, f5.y * wgt, f5.z * wgt, f5.w * wgt);
        }
    }
    WSYNC();

    // ---- packed aggregate over 39 neighbors: lanes 0..43 ----
    float aggv = 0.f;
    if (lane < 2 * PP) {
        int c = (lane < PP) ? lane : lane - PP;
        float mx = -INF, sm = 0.f;
        for (int k = 0; k < KSEL; ++k) {
            float v = fstage[k * PPAD + c];
            mx = fmaxf(mx, v);
            sm += v;
        }
        aggv = (lane < PP) ? mx : sm * (1.f / (float)KSEL);
    }
    WSYNC();
    return aggv;
}

// ---------------- main: one wave per FOUR queries, fused epilogue ----------------
__global__ __launch_bounds__(WPB * 64, 8) void gn_main(
    const float* __restrict__ x,
    const float* __restrict__ Wo, const float* __restrict__ bo,
    const float* __restrict__ coords4,
    const float* __restrict__ feats,
    float* __restrict__ out)
{
    __shared__ unsigned short sel_s[WPB * QW * CAP];     // candidate indices
    __shared__ float fstage_s[WPB * KSEL * PPAD];
    __shared__ unsigned cnt_s[WPB * QW];                 // compact slot counters

    const float INF = __builtin_inff();
    const int wv    = threadIdx.x >> 6;
    const int lane  = threadIdx.x & 63;
    const int qbase = (blockIdx.x * WPB + wv) * QW;      // 4 queries, same batch
    const int b     = qbase >> 12;
    const int n0    = qbase & (NN - 1);
    unsigned short* selp = sel_s + wv * QW * CAP;
    unsigned* cnt = cnt_s + wv * QW;
    float* fstage = fstage_s + wv * (KSEL * PPAD);

    const float4* c4 = ((const float4*)coords4) + (size_t)b * NN;

    if (lane < QW) cnt[lane] = 0;

    // hoisted -2*q components (query coords NOT kept live -- tails reload them).
    // e = s2 - 2*dot with s2 recomputed (bit-identical chain). Selection in
    // e-domain; widened bound keeps an exact superset; tails re-rank exactly.
    float4 cq0 = c4[n0 + 0], cq1 = c4[n0 + 1], cq2 = c4[n0 + 2], cq3 = c4[n0 + 3];
    float m2x0 = -2.f * cq0.x, m2y0 = -2.f * cq0.y, m2z0 = -2.f * cq0.z, m2w0 = -2.f * cq0.w;
    float m2x1 = -2.f * cq1.x, m2y1 = -2.f * cq1.y, m2z1 = -2.f * cq1.z, m2w1 = -2.f * cq1.w;
    float m2x2 = -2.f * cq2.x, m2y2 = -2.f * cq2.y, m2z2 = -2.f * cq2.z, m2w2 = -2.f * cq2.w;
    float m2x3 = -2.f * cq3.x, m2y3 = -2.f * cq3.y, m2z3 = -2.f * cq3.z, m2w3 = -2.f * cq3.w;

    // ---- pass 1: per-query running min of e (self included) ----
    float km0 = INF, km1 = INF, km2 = INF, km3 = INF;
    #pragma unroll 4
    for (int i = 0; i < 64; ++i) {
        float4 cm = c4[i * 64 + lane];
        float s2  = sq4(cm);
        float e0 = fmaf(m2x0, cm.x, fmaf(m2y0, cm.y, fmaf(m2z0, cm.z, fmaf(m2w0, cm.w, s2))));
        float e1 = fmaf(m2x1, cm.x, fmaf(m2y1, cm.y, fmaf(m2z1, cm.z, fmaf(m2w1, cm.w, s2))));
        float e2 = fmaf(m2x2, cm.x, fmaf(m2y2, cm.y, fmaf(m2z2, cm.z, fmaf(m2w2, cm.w, s2))));
        float e3 = fmaf(m2x3, cm.x, fmaf(m2y3, cm.y, fmaf(m2z3, cm.z, fmaf(m2w3, cm.w, s2))));
        km0 = fminf(km0, e0);
        km1 = fminf(km1, e1);
        km2 = fminf(km2, e2);
        km3 = fminf(km3, e3);
    }
    unsigned kb0 = ford(km0), kb1 = ford(km1), kb2 = ford(km2), kb3 = ford(km3);

    // ---- bound: 40th-smallest lane-min key, TRUNCATED radix (bits 31..15),
    //      widen low 15 bits -> guaranteed >= exact 40th e. Exact superset.
    unsigned ub0 = 0, ub1 = 0, ub2 = 0, ub3 = 0;
    for (int bit = 31; bit >= 15; --bit) {
        unsigned msk = 1u << bit;
        unsigned t0 = ub0 | msk, t1 = ub1 | msk, t2 = ub2 | msk, t3 = ub3 | msk;
        if ((int)__popcll(__ballot(kb0 < t0)) < KSEL + 1) ub0 = t0;
        if ((int)__popcll(__ballot(kb1 < t1)) < KSEL + 1) ub1 = t1;
        if ((int)__popcll(__ballot(kb2 < t2)) < KSEL + 1) ub2 = t2;
        if ((int)__popcll(__ballot(kb3 < t3)) < KSEL + 1) ub3 = t3;
    }
    float UBe0 = funord(ub0 | 0x7FFFu);
    float UBe1 = funord(ub1 | 0x7FFFu);
    float UBe2 = funord(ub2 | 0x7FFFu);
    float UBe3 = funord(ub3 | 0x7FFFu);

    // selves all sit in iteration iSelf at lanes l0..l0+3 (n0 % 4 == 0)
    const int iSelf = n0 >> 6;
    const int l0    = n0 & 63;
    WSYNC();                                   // cnt init visible (wave-local)

    // ---- compact pass: LDS atomic slot assignment (VALU -> LDS-pipe trade) ----
    #pragma unroll 4
    for (int i = 0; i < 64; ++i) {
        int m = i * 64 + lane;
        float4 cm = c4[m];
        float s2  = sq4(cm);
        float e0 = fmaf(m2x0, cm.x, fmaf(m2y0, cm.y, fmaf(m2z0, cm.z, fmaf(m2w0, cm.w, s2))));
        float e1 = fmaf(m2x1, cm.x, fmaf(m2y1, cm.y, fmaf(m2z1, cm.z, fmaf(m2w1, cm.w, s2))));
        float e2 = fmaf(m2x2, cm.x, fmaf(m2y2, cm.y, fmaf(m2z2, cm.z, fmaf(m2w2, cm.w, s2))));
        float e3 = fmaf(m2x3, cm.x, fmaf(m2y3, cm.y, fmaf(m2z3, cm.z, fmaf(m2w3, cm.w, s2))));
        bool t0 = (e0 <= UBe0);
        bool t1 = (e1 <= UBe1);
        bool t2 = (e2 <= UBe2);
        bool t3 = (e3 <= UBe3);
        if (i == iSelf) {                      // wave-uniform, 1 of 64 iters
            t0 = t0 && (lane != l0 + 0);
            t1 = t1 && (lane != l0 + 1);
            t2 = t2 && (lane != l0 + 2);
            t3 = t3 && (lane != l0 + 3);
        }
        if (t0) {
            unsigned s = atomicAdd(&cnt[0], 1u) & (CAP - 1);
            selp[0 * CAP + s] = (unsigned short)m;
        }
        if (t1) {
            unsigned s = atomicAdd(&cnt[1], 1u) & (CAP - 1);
            selp[1 * CAP + s] = (unsigned short)m;
        }
        if (t2) {
            unsigned s = atomicAdd(&cnt[2], 1u) & (CAP - 1);
            selp[2 * CAP + s] = (unsigned short)m;
        }
        if (t3) {
            unsigned s = atomicAdd(&cnt[3], 1u) & (CAP - 1);
            selp[3 * CAP + s] = (unsigned short)m;
        }
    }
    WSYNC();
    int cc0 = (int)cnt[0];
    int cc1 = (int)cnt[1];
    int cc2 = (int)cnt[2];
    int cc3 = (int)cnt[3];
    WSYNC();

    // ---- four selection/aggregate tails (packed agg kept in VGPRs) ----
    float agg0 = tail_select(lane, b, n0 + 0, cc0, selp + 0 * CAP, c4, feats, fstage);
    float agg1 = tail_select(lane, b, n0 + 1, cc1, selp + 1 * CAP, c4, feats, fstage);
    float agg2 = tail_select(lane, b, n0 + 2, cc2, selp + 2 * CAP, c4, feats, fstage);
    float agg3 = tail_select(lane, b, n0 + 3, cc3, selp + 3 * CAP, c4, feats, fstage);

    // ---- FUSED epilogue: Wo loaded ONCE for all 4 queries; x via scalar loads ----
    const int qbU = __builtin_amdgcn_readfirstlane(qbase);
    const float* xu = x + (size_t)qbU * FIN;             // uniform -> SMEM loads
    if (lane < FOUT) {
        const float* woL = Wo + lane;
        float bb = bo[lane];
        float a00 = bb, a01 = 0.f, a02 = 0.f, a03 = 0.f;
        float a10 = bb, a11 = 0.f, a12 = 0.f, a13 = 0.f;
        float a20 = bb, a21 = 0.f, a22 = 0.f, a23 = 0.f;
        float a30 = bb, a31 = 0.f, a32 = 0.f, a33 = 0.f;
        #pragma unroll
        for (int f = 0; f < FIN; f += 4) {
            float w0 = woL[(f + 0) * FOUT];
            float w1 = woL[(f + 1) * FOUT];
            float w2 = woL[(f + 2) * FOUT];
            float w3 = woL[(f + 3) * FOUT];
            a00 = fmaf(xu[0 * FIN + f + 0], w0, a00);
            a01 = fmaf(xu[0 * FIN + f + 1], w1, a01);
            a02 = fmaf(xu[0 * FIN + f + 2], w2, a02);
            a03 = fmaf(xu[0 * FIN + f + 3], w3, a03);
            a10 = fmaf(xu[1 * FIN + f + 0], w0, a10);
            a11 = fmaf(xu[1 * FIN + f + 1], w1, a11);
            a12 = fmaf(xu[1 * FIN + f + 2], w2, a12);
            a13 = fmaf(xu[1 * FIN + f + 3], w3, a13);
            a20 = fmaf(xu[2 * FIN + f + 0], w0, a20);
            a21 = fmaf(xu[2 * FIN + f + 1], w1, a21);
            a22 = fmaf(xu[2 * FIN + f + 2], w2, a22);
            a23 = fmaf(xu[2 * FIN + f + 3], w3, a23);
            a30 = fmaf(xu[3 * FIN + f + 0], w0, a30);
            a31 = fmaf(xu[3 * FIN + f + 1], w1, a31);
            a32 = fmaf(xu[3 * FIN + f + 2], w2, a32);
            a33 = fmaf(xu[3 * FIN + f + 3], w3, a33);
        }
        #pragma unroll
        for (int g = 0; g < 2 * PP; g += 4) {
            float w0 = woL[(FIN + g + 0) * FOUT];
            float w1 = woL[(FIN + g + 1) * FOUT];
            float w2 = woL[(FIN + g + 2) * FOUT];
            float w3 = woL[(FIN + g + 3) * FOUT];
            a00 = fmaf(lane_bcast(agg0, g + 0), w0, a00);
            a01 = fmaf(lane_bcast(agg0, g + 1), w1, a01);
            a02 = fmaf(lane_bcast(agg0, g + 2), w2, a02);
            a03 = fmaf(lane_bcast(agg0, g + 3), w3, a03);
            a10 = fmaf(lane_bcast(agg1, g + 0), w0, a10);
            a11 = fmaf(lane_bcast(agg1, g + 1), w1, a11);
            a12 = fmaf(lane_bcast(agg1, g + 2), w2, a12);
            a13 = fmaf(lane_bcast(agg1, g + 3), w3, a13);
            a20 = fmaf(lane_bcast(agg2, g + 0), w0, a20);
            a21 = fmaf(lane_bcast(agg2, g + 1), w1, a21);
            a22 = fmaf(lane_bcast(agg2, g + 2), w2, a22);
            a23 = fmaf(lane_bcast(agg2, g + 3), w3, a23);
            a30 = fmaf(lane_bcast(agg3, g + 0), w0, a30);
            a31 = fmaf(lane_bcast(agg3, g + 1), w1, a31);
            a32 = fmaf(lane_bcast(agg3, g + 2), w2, a32);
            a33 = fmaf(lane_bcast(agg3, g + 3), w3, a33);
        }
        float ac0 = (a00 + a01) + (a02 + a03);
        float ac1 = (a10 + a11) + (a12 + a13);
        float ac2 = (a20 + a21) + (a22 + a23);
        float ac3 = (a30 + a31) + (a32 + a33);
        float e0 = __expf(2.f * ac0);
        float e1 = __expf(2.f * ac1);
        float e2 = __expf(2.f * ac2);
        float e3 = __expf(2.f * ac3);
        float r0 = __builtin_amdgcn_rcpf(e0 + 1.f);
        float r1 = __builtin_amdgcn_rcpf(e1 + 1.f);
        float r2 = __builtin_amdgcn_rcpf(e2 + 1.f);
        float r3 = __builtin_amdgcn_rcpf(e3 + 1.f);
        out[(size_t)(qbU + 0) * FOUT + lane] = fmaf(-2.f, r0, 1.f);
        out[(size_t)(qbU + 1) * FOUT + lane] = fmaf(-2.f, r1, 1.f);
        out[(size_t)(qbU + 2) * FOUT + lane] = fmaf(-2.f, r2, 1.f);
        out[(size_t)(qbU + 3) * FOUT + lane] = fmaf(-2.f, r3, 1.f);
    }
}

extern "C" void kernel_launch(void* const* d_in, const int* in_sizes, int n_in,
                              void* d_out, int out_size, void* d_ws, size_t ws_size,
                              hipStream_t stream) {
    const float* x  = (const float*)d_in[0];
    const float* Wf = (const float*)d_in[1];
    const float* bf = (const float*)d_in[2];
    const float* Ws = (const float*)d_in[3];
    const float* bs = (const float*)d_in[4];
    const float* Wo = (const float*)d_in[5];
    const float* bo = (const float*)d_in[6];
    float* outp = (float*)d_out;

    float* ws      = (float*)d_ws;
    float* coords4 = ws;                      // 32768*4  = 131072 floats
    float* feats   = ws + 131072;             // 32768*24 = 786432 floats

    gn_pre<<<(32768 * 4) / 256, 256, 0, stream>>>(x, Wf, bf, Ws, bs, coords4, feats);
    gn_main<<<32768 / (WPB * QW), WPB * 64, 0, stream>>>(x, Wo, bo, coords4, feats, outp);
}

// Round 12
// 147.483 us; speedup vs baseline: 1.1486x; 1.0007x over previous
//
#include <hip/hip_runtime.h>
#include <cmath>

#define NN    4096
#define FIN   32
#define KSEL  39      // neighbors kept (top-40 minus self)
#define PP    22
#define PPAD  24
#define FOUT  48
#define WPB   2       // waves per block
#define QW    4       // queries per wave
#define CAP   128     // candidate cap per query (fallback if exceeded)
#define WCOLS 32      // combined weight columns: [Wf(22) | pad(2) | Ws(4) | pad(4)]

#define WSYNC() asm volatile("s_waitcnt lgkmcnt(0)" ::: "memory")

__device__ __forceinline__ int lane_prefix(unsigned long long m) {
    return __builtin_amdgcn_mbcnt_hi((unsigned)(m >> 32),
           __builtin_amdgcn_mbcnt_lo((unsigned)m, 0));
}
// order-preserving float->uint map (total order, handles negatives)
__device__ __forceinline__ unsigned ford(float f) {
    int u = __float_as_int(f);
    return (u >= 0) ? ((unsigned)u | 0x80000000u) : ~(unsigned)u;
}
__device__ __forceinline__ float funord(unsigned k) {
    unsigned v = (k & 0x80000000u) ? (k & 0x7FFFFFFFu) : ~k;
    return __uint_as_float(v);
}
// broadcast lane l's value (l must be wave-uniform; here a literal)
__device__ __forceinline__ float lane_bcast(float v, int l) {
    return __uint_as_float((unsigned)__builtin_amdgcn_readlane((int)__float_as_uint(v), l));
}
// |c|^2 with the EXACT gn_pre FMA order (bit-identical everywhere)
__device__ __forceinline__ float sq4(float4 c) {
    return fmaf(c.x, c.x, fmaf(c.y, c.y, fmaf(c.z, c.z, c.w * c.w)));
}

// ---------------- precompute: 4 threads per point, LDS-staged weights ------------
__global__ __launch_bounds__(256) void gn_pre(
    const float* __restrict__ x,
    const float* __restrict__ Wf, const float* __restrict__ bf,
    const float* __restrict__ Ws, const float* __restrict__ bs,
    float* __restrict__ coords4, float* __restrict__ feats)
{
    __shared__ __align__(16) float sW[FIN * WCOLS];
    __shared__ float sB[WCOLS];

    int t = threadIdx.x;
    for (int idx = t; idx < FIN * WCOLS; idx += 256) {
        int i = idx >> 5, c = idx & 31;
        float v = 0.f;
        if (c < PP) v = Wf[i * PP + c];
        else if (c >= 24 && c < 28) v = Ws[i * 4 + (c - 24)];
        sW[idx] = v;
    }
    if (t < WCOLS) {
        float v = 0.f;
        if (t < PP) v = bf[t];
        else if (t >= 24 && t < 28) v = bs[t - 24];
        sB[t] = v;
    }
    __syncthreads();

    int gid = blockIdx.x * 256 + t;
    int p = gid >> 2;          // point
    int h = gid & 3;           // column strip
    int c0 = h * 8;

    const float4* xr4 = (const float4*)(x + (size_t)p * FIN);
    float acc[8];
    #pragma unroll
    for (int k = 0; k < 8; ++k) acc[k] = sB[c0 + k];

    #pragma unroll
    for (int i = 0; i < 8; ++i) {
        float4 xt = xr4[i];
        const float* w0 = sW + (4 * i + 0) * WCOLS + c0;
        const float* w1 = sW + (4 * i + 1) * WCOLS + c0;
        const float* w2 = sW + (4 * i + 2) * WCOLS + c0;
        const float* w3 = sW + (4 * i + 3) * WCOLS + c0;
        #pragma unroll
        for (int k = 0; k < 8; ++k) acc[k] = fmaf(xt.x, w0[k], acc[k]);
        #pragma unroll
        for (int k = 0; k < 8; ++k) acc[k] = fmaf(xt.y, w1[k], acc[k]);
        #pragma unroll
        for (int k = 0; k < 8; ++k) acc[k] = fmaf(xt.z, w2[k], acc[k]);
        #pragma unroll
        for (int k = 0; k < 8; ++k) acc[k] = fmaf(xt.w, w3[k], acc[k]);
    }

    if (h < 3) {
        float4* fw = (float4*)(feats + (size_t)p * PPAD + c0);
        fw[0] = make_float4(acc[0], acc[1], acc[2], acc[3]);
        fw[1] = make_float4(acc[4], acc[5], acc[6], acc[7]);   // h=2: cols 22,23 exact 0
    } else {
        ((float4*)coords4)[p] = make_float4(acc[0], acc[1], acc[2], acc[3]);
    }
}

// ---- fallback-only helpers (degenerate C > CAP path) ----------------------------
__device__ __forceinline__ void sort64_pair(float& v, int& m, int lane) {
    #pragma unroll
    for (int k = 2; k <= 64; k <<= 1) {
        #pragma unroll
        for (int j = k >> 1; j >= 1; j >>= 1) {
            float ov = __shfl_xor(v, j);
            int   om = __shfl_xor(m, j);
            bool keepMin = (((lane & j) == 0) == ((lane & k) == 0));
            bool less = (ov < v) || (ov == v && om < m);
            bool take = (less == keepMin);
            v = take ? ov : v;
            m = take ? om : m;
        }
    }
}
__device__ __forceinline__ void merge64(float& Lv, int& Lm, float cv, int cm, int lane) {
    float rv = __shfl_xor(cv, 63);
    int   rm = __shfl_xor(cm, 63);
    bool less = (rv < Lv) || (rv == Lv && rm < Lm);
    if (less) { Lv = rv; Lm = rm; }
    #pragma unroll
    for (int j = 32; j >= 1; j >>= 1) {
        float ov = __shfl_xor(Lv, j);
        int   om = __shfl_xor(Lm, j);
        bool lower = ((lane & j) == 0);
        bool l2 = (ov < Lv) || (ov == Lv && om < Lm);
        bool take = (l2 == lower);
        Lv = take ? ov : Lv;
        Lm = take ? om : Lm;
    }
}

// ------- per-query selection + staging + packed aggregate (NO epilogue here) -----
// Selection math bit-identical to the verified kernel; s2 recomputed (same bits).
// C <= 64 single-slot fast path: kd1 would be all-invalid (0xFFFFFFFF never < t
// for t < 2^31, never ties D, never takes), so dropping slot 1 is exactly
// equivalent -- every radix count, tie count, and staged value is unchanged.
// Returns packed agg: lane c<22 -> max_c ; lane 22+c -> mean_c ; others 0.
__device__ __forceinline__ float tail_select(
    int lane, int b, int nj, int C,
    const unsigned short* __restrict__ selq,
    const float4* __restrict__ c4,
    const float* __restrict__ feats,
    float* __restrict__ fstage)
{
    const float INF = __builtin_inff();
    float4 cqj = c4[nj];
    float sqnj = sq4(cqj);
    C = __builtin_amdgcn_readfirstlane(C);   // wave-uniform -> scalar branch

    if (C <= 64) {
        // ---- single-slot fast path (exactly equivalent, ~40% fewer tail ops) ----
        unsigned kd0 = 0xFFFFFFFFu, ki0 = 0xFFFFFFFFu; float dv0 = 0.f;
        if (lane < C) {
            unsigned idx = (unsigned)selq[lane];
            float4 cm = c4[idx];
            float s2 = sq4(cm);
            float dt = fmaf(cqj.x, cm.x, fmaf(cqj.y, cm.y, fmaf(cqj.z, cm.z, cqj.w * cm.w)));
            float d  = fmaxf(fmaf(-2.f, dt, s2 + sqnj), 0.f);
            dv0 = d; kd0 = __float_as_uint(d); ki0 = idx;
        }
        unsigned D = 0;
        for (int bit = 30; bit >= 0; --bit) {
            unsigned t = D | (1u << bit);
            int c = (int)__popcll(__ballot(kd0 < t));
            if (c < KSEL) D = t;
        }
        int cless  = (int)__popcll(__ballot(kd0 < D));
        int tiecnt = (int)__popcll(__ballot(kd0 == D));
        int tneed = KSEL - cless;
        unsigned TI = 0xFFFFFFFFu;
        if (tiecnt > tneed) {            // rare: resolve ties by lowest index
            unsigned pi = 0;
            for (int bit = 11; bit >= 0; --bit) {
                unsigned t = pi | (1u << bit);
                int c = (int)__popcll(__ballot((kd0 == D) && (ki0 < t)));
                if (c < tneed) pi = t;
            }
            TI = pi;
        }
        bool take0 = (kd0 < D) || ((kd0 == D) && (ki0 <= TI));
        unsigned long long tb0 = __ballot(take0);
        if (take0) {
            unsigned slot = (unsigned)lane_prefix(tb0);
            float wgt = __expf(-10.f * dv0);
            const float4* fr = (const float4*)(feats + ((size_t)b * NN + ki0) * PPAD);
            float4 f0 = fr[0], f1 = fr[1], f2 = fr[2], f3 = fr[3], f4 = fr[4], f5 = fr[5];
            float4* row = (float4*)(fstage + slot * PPAD);
            row[0] = make_float4(f0.x * wgt, f0.y * wgt, f0.z * wgt, f0.w * wgt);
            row[1] = make_float4(f1.x * wgt, f1.y * wgt, f1.z * wgt, f1.w * wgt);
            row[2] = make_float4(f2.x * wgt, f2.y * wgt, f2.z * wgt, f2.w * wgt);
            row[3] = make_float4(f3.x * wgt, f3.y * wgt, f3.z * wgt, f3.w * wgt);
            row[4] = make_float4(f4.x * wgt, f4.y * wgt, f4.z * wgt, f4.w * wgt);
            row[5] = make_float4(f5.x * wgt, f5.y * wgt, f5.z * wgt, f5.w * wgt);
        }
    } else if (C <= CAP) {
        // ---- two-slot path (verbatim round-8) ----
        unsigned kd0 = 0xFFFFFFFFu, ki0 = 0xFFFFFFFFu; float dv0 = 0.f;
        if (lane < C) {
            unsigned idx = (unsigned)selq[lane];
            float4 cm = c4[idx];
            float s2 = sq4(cm);
            float dt = fmaf(cqj.x, cm.x, fmaf(cqj.y, cm.y, fmaf(cqj.z, cm.z, cqj.w * cm.w)));
            float d  = fmaxf(fmaf(-2.f, dt, s2 + sqnj), 0.f);
            dv0 = d; kd0 = __float_as_uint(d); ki0 = idx;
        }
        unsigned kd1 = 0xFFFFFFFFu, ki1 = 0xFFFFFFFFu; float dv1 = 0.f;
        if (64 + lane < C) {
            unsigned idx = (unsigned)selq[64 + lane];
            float4 cm = c4[idx];
            float s2 = sq4(cm);
            float dt = fmaf(cqj.x, cm.x, fmaf(cqj.y, cm.y, fmaf(cqj.z, cm.z, cqj.w * cm.w)));
            float d  = fmaxf(fmaf(-2.f, dt, s2 + sqnj), 0.f);
            dv1 = d; kd1 = __float_as_uint(d); ki1 = idx;
        }
        // D = exact 39th-smallest clamped d2 bits (must stay exact)
        unsigned D = 0;
        for (int bit = 30; bit >= 0; --bit) {
            unsigned t = D | (1u << bit);
            int c = (int)__popcll(__ballot(kd0 < t))
                  + (int)__popcll(__ballot(kd1 < t));
            if (c < KSEL) D = t;
        }
        int cless  = (int)__popcll(__ballot(kd0 < D))
                   + (int)__popcll(__ballot(kd1 < D));
        int tiecnt = (int)__popcll(__ballot(kd0 == D))
                   + (int)__popcll(__ballot(kd1 == D));
        int tneed = KSEL - cless;
        unsigned TI = 0xFFFFFFFFu;
        if (tiecnt > tneed) {            // rare: resolve ties by lowest index
            unsigned pi = 0;
            for (int bit = 11; bit >= 0; --bit) {
                unsigned t = pi | (1u << bit);
                int c = (int)__popcll(__ballot((kd0 == D) && (ki0 < t)))
                      + (int)__popcll(__ballot((kd1 == D) && (ki1 < t)));
                if (c < tneed) pi = t;
            }
            TI = pi;
        }
        bool take0 = (kd0 < D) || ((kd0 == D) && (ki0 <= TI));
        bool take1 = (kd1 < D) || ((kd1 == D) && (ki1 <= TI));
        unsigned long long tb0 = __ballot(take0);
        unsigned long long tb1 = __ballot(take1);
        unsigned base1 = (unsigned)__popcll(tb0);
        if (take0) {
            unsigned slot = (unsigned)lane_prefix(tb0);
            float wgt = __expf(-10.f * dv0);
            const float4* fr = (const float4*)(feats + ((size_t)b * NN + ki0) * PPAD);
            float4 f0 = fr[0], f1 = fr[1], f2 = fr[2], f3 = fr[3], f4 = fr[4], f5 = fr[5];
            float4* row = (float4*)(fstage + slot * PPAD);
            row[0] = make_float4(f0.x * wgt, f0.y * wgt, f0.z * wgt, f0.w * wgt);
            row[1] = make_float4(f1.x * wgt, f1.y * wgt, f1.z * wgt, f1.w * wgt);
            row[2] = make_float4(f2.x * wgt, f2.y * wgt, f2.z * wgt, f2.w * wgt);
            row[3] = make_float4(f3.x * wgt, f3.y * wgt, f3.z * wgt, f3.w * wgt);
            row[4] = make_float4(f4.x * wgt, f4.y * wgt, f4.z * wgt, f4.w * wgt);
            row[5] = make_float4(f5.x * wgt, f5.y * wgt, f5.z * wgt, f5.w * wgt);
        }
        if (take1) {
            unsigned slot = base1 + (unsigned)lane_prefix(tb1);
            float wgt = __expf(-10.f * dv1);
            const float4* fr = (const float4*)(feats + ((size_t)b * NN + ki1) * PPAD);
            float4 f0 = fr[0], f1 = fr[1], f2 = fr[2], f3 = fr[3], f4 = fr[4], f5 = fr[5];
            float4* row = (float4*)(fstage + slot * PPAD);
            row[0] = make_float4(f0.x * wgt, f0.y * wgt, f0.z * wgt, f0.w * wgt);
            row[1] = make_float4(f1.x * wgt, f1.y * wgt, f1.z * wgt, f1.w * wgt);
            row[2] = make_float4(f2.x * wgt, f2.y * wgt, f2.z * wgt, f2.w * wgt);
            row[3] = make_float4(f3.x * wgt, f3.y * wgt, f3.z * wgt, f3.w * wgt);
            row[4] = make_float4(f4.x * wgt, f4.y * wgt, f4.z * wgt, f4.w * wgt);
            row[5] = make_float4(f5.x * wgt, f5.y * wgt, f5.z * wgt, f5.w * wgt);
        }
    } else {
        // degenerate fallback: exact streaming top-64 over all 4096
        float Lv = INF; int Lm = 0x7FFFFFFF;
        for (int c = 0; c < 64; ++c) {
            int m = c * 64 + lane;
            float4 cm = c4[m];
            float s2 = sq4(cm);
            float dt = fmaf(cqj.x, cm.x, fmaf(cqj.y, cm.y, fmaf(cqj.z, cm.z, cqj.w * cm.w)));
            float v  = fmaxf(fmaf(-2.f, dt, s2 + sqnj), 0.f);
            if (m == nj) v = INF;
            sort64_pair(v, m, lane);
            if (c == 0) { Lv = v; Lm = m; }
            else        merge64(Lv, Lm, v, m, lane);
        }
        if (lane < KSEL) {
            float wgt = __expf(-10.f * Lv);
            const float4* fr = (const float4*)(feats + ((size_t)b * NN + Lm) * PPAD);
            float4 f0 = fr[0], f1 = fr[1], f2 = fr[2], f3 = fr[3], f4 = fr[4], f5 = fr[5];
            float4* row = (float4*)(fstage + lane * PPAD);
            row[0] = make_float4(f0.x * wgt, f0.y * wgt, f0.z * wgt, f0.w * wgt);
            row[1] = make_float4(f1.x * wgt, f1.y * wgt, f1.z * wgt, f1.w * wgt);
            row[2] = make_float4(f2.x * wgt, f2.y * wgt, f2.z * wgt, f2.w * wgt);
            row[3] = make_float4(f3.x * wgt, f3.y * wgt, f3.z * wgt, f3.w * wgt);
            row[4] = make_float4(f4.x * wgt, f4.y * wgt, f4.z * wgt, f4.w * wgt);
            row[5] = make_float4(f5.x * wgt, f5.y * wgt, f5.z * wgt, f5.w * wgt);
        }
    }
    WSYNC();

    // ---- packed aggregate over 39 neighbors: lanes 0..43 ----
    float aggv = 0.f;
    if (lane < 2 * PP) {
        int c = (lane < PP) ? lane : lane - PP;
        float mx = -INF, sm = 0.f;
        for (int k = 0; k < KSEL; ++k) {
            float v = fstage[k * PPAD + c];
            mx = fmaxf(mx, v);
            sm += v;
        }
        aggv = (lane < PP) ? mx : sm * (1.f / (float)KSEL);
    }
    WSYNC();
    return aggv;
}

// ---------------- main: one wave per FOUR queries, fused epilogue ----------------
__global__ __launch_bounds__(WPB * 64, 8) void gn_main(
    const float* __restrict__ x,
    const float* __restrict__ Wo, const float* __restrict__ bo,
    const float* __restrict__ coords4,
    const float* __restrict__ feats,
    float* __restrict__ out)
{
    __shared__ unsigned short sel_s[WPB * QW * CAP];     // candidate indices
    __shared__ float fstage_s[WPB * KSEL * PPAD];
    __shared__ unsigned cnt_s[WPB * QW];                 // compact slot counters

    const float INF = __builtin_inff();
    const int wv    = threadIdx.x >> 6;
    const int lane  = threadIdx.x & 63;
    const int qbase = (blockIdx.x * WPB + wv) * QW;      // 4 queries, same batch
    const int b     = qbase >> 12;
    const int n0    = qbase & (NN - 1);
    unsigned short* selp = sel_s + wv * QW * CAP;
    unsigned* cnt = cnt_s + wv * QW;
    float* fstage = fstage_s + wv * (KSEL * PPAD);

    const float4* c4 = ((const float4*)coords4) + (size_t)b * NN;

    if (lane < QW) cnt[lane] = 0;

    // hoisted -2*q components (query coords NOT kept live -- tails reload them).
    // e = s2 - 2*dot with s2 recomputed (bit-identical chain). Selection in
    // e-domain; widened bound keeps an exact superset; tails re-rank exactly.
    float4 cq0 = c4[n0 + 0], cq1 = c4[n0 + 1], cq2 = c4[n0 + 2], cq3 = c4[n0 + 3];
    float m2x0 = -2.f * cq0.x, m2y0 = -2.f * cq0.y, m2z0 = -2.f * cq0.z, m2w0 = -2.f * cq0.w;
    float m2x1 = -2.f * cq1.x, m2y1 = -2.f * cq1.y, m2z1 = -2.f * cq1.z, m2w1 = -2.f * cq1.w;
    float m2x2 = -2.f * cq2.x, m2y2 = -2.f * cq2.y, m2z2 = -2.f * cq2.z, m2w2 = -2.f * cq2.w;
    float m2x3 = -2.f * cq3.x, m2y3 = -2.f * cq3.y, m2z3 = -2.f * cq3.z, m2w3 = -2.f * cq3.w;

    // ---- pass 1: per-query running min of e (self included) ----
    float km0 = INF, km1 = INF, km2 = INF, km3 = INF;
    #pragma unroll 4
    for (int i = 0; i < 64; ++i) {
        float4 cm = c4[i * 64 + lane];
        float s2  = sq4(cm);
        float e0 = fmaf(m2x0, cm.x, fmaf(m2y0, cm.y, fmaf(m2z0, cm.z, fmaf(m2w0, cm.w, s2))));
        float e1 = fmaf(m2x1, cm.x, fmaf(m2y1, cm.y, fmaf(m2z1, cm.z, fmaf(m2w1, cm.w, s2))));
        float e2 = fmaf(m2x2, cm.x, fmaf(m2y2, cm.y, fmaf(m2z2, cm.z, fmaf(m2w2, cm.w, s2))));
        float e3 = fmaf(m2x3, cm.x, fmaf(m2y3, cm.y, fmaf(m2z3, cm.z, fmaf(m2w3, cm.w, s2))));
        km0 = fminf(km0, e0);
        km1 = fminf(km1, e1);
        km2 = fminf(km2, e2);
        km3 = fminf(km3, e3);
    }
    unsigned kb0 = ford(km0), kb1 = ford(km1), kb2 = ford(km2), kb3 = ford(km3);

    // ---- bound: 40th-smallest lane-min key, TRUNCATED radix (bits 31..15),
    //      widen low 15 bits -> guaranteed >= exact 40th e. Exact superset.
    unsigned ub0 = 0, ub1 = 0, ub2 = 0, ub3 = 0;
    for (int bit = 31; bit >= 15; --bit) {
        unsigned msk = 1u << bit;
        unsigned t0 = ub0 | msk, t1 = ub1 | msk, t2 = ub2 | msk, t3 = ub3 | msk;
        if ((int)__popcll(__ballot(kb0 < t0)) < KSEL + 1) ub0 = t0;
        if ((int)__popcll(__ballot(kb1 < t1)) < KSEL + 1) ub1 = t1;
        if ((int)__popcll(__ballot(kb2 < t2)) < KSEL + 1) ub2 = t2;
        if ((int)__popcll(__ballot(kb3 < t3)) < KSEL + 1) ub3 = t3;
    }
    float UBe0 = funord(ub0 | 0x7FFFu);
    float UBe1 = funord(ub1 | 0x7FFFu);
    float UBe2 = funord(ub2 | 0x7FFFu);
    float UBe3 = funord(ub3 | 0x7FFFu);

    // selves all sit in iteration iSelf at lanes l0..l0+3 (n0 % 4 == 0)
    const int iSelf = n0 >> 6;
    const int l0    = n0 & 63;
    WSYNC();                                   // cnt init visible (wave-local)

    // ---- compact pass: LDS atomic slot assignment (VALU -> LDS-pipe trade) ----
    #pragma unroll 4
    for (int i = 0; i < 64; ++i) {
        int m = i * 64 + lane;
        float4 cm = c4[m];
        float s2  = sq4(cm);
        float e0 = fmaf(m2x0, cm.x, fmaf(m2y0, cm.y, fmaf(m2z0, cm.z, fmaf(m2w0, cm.w, s2))));
        float e1 = fmaf(m2x1, cm.x, fmaf(m2y1, cm.y, fmaf(m2z1, cm.z, fmaf(m2w1, cm.w, s2))));
        float e2 = fmaf(m2x2, cm.x, fmaf(m2y2, cm.y, fmaf(m2z2, cm.z, fmaf(m2w2, cm.w, s2))));
        float e3 = fmaf(m2x3, cm.x, fmaf(m2y3, cm.y, fmaf(m2z3, cm.z, fmaf(m2w3, cm.w, s2))));
        bool t0 = (e0 <= UBe0);
        bool t1 = (e1 <= UBe1);
        bool t2 = (e2 <= UBe2);
        bool t3 = (e3 <= UBe3);
        if (i == iSelf) {                      // wave-uniform, 1 of 64 iters
            t0 = t0 && (lane != l0 + 0);
            t1 = t1 && (lane != l0 + 1);
            t2 = t2 && (lane != l0 + 2);
            t3 = t3 && (lane != l0 + 3);
        }
        if (t0) {
            unsigned s = atomicAdd(&cnt[0], 1u) & (CAP - 1);
            selp[0 * CAP + s] = (unsigned short)m;
        }
        if (t1) {
            unsigned s = atomicAdd(&cnt[1], 1u) & (CAP - 1);
            selp[1 * CAP + s] = (unsigned short)m;
        }
        if (t2) {
            unsigned s = atomicAdd(&cnt[2], 1u) & (CAP - 1);
            selp[2 * CAP + s] = (unsigned short)m;
        }
        if (t3) {
            unsigned s = atomicAdd(&cnt[3], 1u) & (CAP - 1);
            selp[3 * CAP + s] = (unsigned short)m;
        }
    }
    WSYNC();
    int cc0 = (int)cnt[0];
    int cc1 = (int)cnt[1];
    int cc2 = (int)cnt[2];
    int cc3 = (int)cnt[3];
    WSYNC();

    // ---- four selection/aggregate tails (packed agg kept in VGPRs) ----
    float agg0 = tail_select(lane, b, n0 + 0, cc0, selp + 0 * CAP, c4, feats, fstage);
    float agg1 = tail_select(lane, b, n0 + 1, cc1, selp + 1 * CAP, c4, feats, fstage);
    float agg2 = tail_select(lane, b, n0 + 2, cc2, selp + 2 * CAP, c4, feats, fstage);
    float agg3 = tail_select(lane, b, n0 + 3, cc3, selp + 3 * CAP, c4, feats, fstage);

    // ---- FUSED epilogue: Wo loaded ONCE for all 4 queries; x via scalar loads ----
    const int qbU = __builtin_amdgcn_readfirstlane(qbase);
    const float* xu = x + (size_t)qbU * FIN;             // uniform -> SMEM loads
    if (lane < FOUT) {
        const float* woL = Wo + lane;
        float bb = bo[lane];
        float a00 = bb, a01 = 0.f, a02 = 0.f, a03 = 0.f;
        float a10 = bb, a11 = 0.f, a12 = 0.f, a13 = 0.f;
        float a20 = bb, a21 = 0.f, a22 = 0.f, a23 = 0.f;
        float a30 = bb, a31 = 0.f, a32 = 0.f, a33 = 0.f;
        #pragma unroll
        for (int f = 0; f < FIN; f += 4) {
            float w0 = woL[(f + 0) * FOUT];
            float w1 = woL[(f + 1) * FOUT];
            float w2 = woL[(f + 2) * FOUT];
            float w3 = woL[(f + 3) * FOUT];
            a00 = fmaf(xu[0 * FIN + f + 0], w0, a00);
            a01 = fmaf(xu[0 * FIN + f + 1], w1, a01);
            a02 = fmaf(xu[0 * FIN + f + 2], w2, a02);
            a03 = fmaf(xu[0 * FIN + f + 3], w3, a03);
            a10 = fmaf(xu[1 * FIN + f + 0], w0, a10);
            a11 = fmaf(xu[1 * FIN + f + 1], w1, a11);
            a12 = fmaf(xu[1 * FIN + f + 2], w2, a12);
            a13 = fmaf(xu[1 * FIN + f + 3], w3, a13);
            a20 = fmaf(xu[2 * FIN + f + 0], w0, a20);
            a21 = fmaf(xu[2 * FIN + f + 1], w1, a21);
            a22 = fmaf(xu[2 * FIN + f + 2], w2, a22);
            a23 = fmaf(xu[2 * FIN + f + 3], w3, a23);
            a30 = fmaf(xu[3 * FIN + f + 0], w0, a30);
            a31 = fmaf(xu[3 * FIN + f + 1], w1, a31);
            a32 = fmaf(xu[3 * FIN + f + 2], w2, a32);
            a33 = fmaf(xu[3 * FIN + f + 3], w3, a33);
        }
        #pragma unroll
        for (int g = 0; g < 2 * PP; g += 4) {
            float w0 = woL[(FIN + g + 0) * FOUT];
            float w1 = woL[(FIN + g + 1) * FOUT];
            float w2 = woL[(FIN + g + 2) * FOUT];
            float w3 = woL[(FIN + g + 3) * FOUT];
            a00 = fmaf(lane_bcast(agg0, g + 0), w0, a00);
            a01 = fmaf(lane_bcast(agg0, g + 1), w1, a01);
            a02 = fmaf(lane_bcast(agg0, g + 2), w2, a02);
            a03 = fmaf(lane_bcast(agg0, g + 3), w3, a03);
            a10 = fmaf(lane_bcast(agg1, g + 0), w0, a10);
            a11 = fmaf(lane_bcast(agg1, g + 1), w1, a11);
            a12 = fmaf(lane_bcast(agg1, g + 2), w2, a12);
            a13 = fmaf(lane_bcast(agg1, g + 3), w3, a13);
            a20 = fmaf(lane_bcast(agg2, g + 0), w0, a20);
            a21 = fmaf(lane_bcast(agg2, g + 1), w1, a21);
            a22 = fmaf(lane_bcast(agg2, g + 2), w2, a22);
            a23 = fmaf(lane_bcast(agg2, g + 3), w3, a23);
            a30 = fmaf(lane_bcast(agg3, g + 0), w0, a30);
            a31 = fmaf(lane_bcast(agg3, g + 1), w1, a31);
            a32 = fmaf(lane_bcast(agg3, g + 2), w2, a32);
            a33 = fmaf(lane_bcast(agg3, g + 3), w3, a33);
        }
        float ac0 = (a00 + a01) + (a02 + a03);
        float ac1 = (a10 + a11) + (a12 + a13);
        float ac2 = (a20 + a21) + (a22 + a23);
        float ac3 = (a30 + a31) + (a32 + a33);
        float e0 = __expf(2.f * ac0);
        float e1 = __expf(2.f * ac1);
        float e2 = __expf(2.f * ac2);
        float e3 = __expf(2.f * ac3);
        float r0 = __builtin_amdgcn_rcpf(e0 + 1.f);
        float r1 = __builtin_amdgcn_rcpf(e1 + 1.f);
        float r2 = __builtin_amdgcn_rcpf(e2 + 1.f);
        float r3 = __builtin_amdgcn_rcpf(e3 + 1.f);
        out[(size_t)(qbU + 0) * FOUT + lane] = fmaf(-2.f, r0, 1.f);
        out[(size_t)(qbU + 1) * FOUT + lane] = fmaf(-2.f, r1, 1.f);
        out[(size_t)(qbU + 2) * FOUT + lane] = fmaf(-2.f, r2, 1.f);
        out[(size_t)(qbU + 3) * FOUT + lane] = fmaf(-2.f, r3, 1.f);
    }
}

extern "C" void kernel_launch(void* const* d_in, const int* in_sizes, int n_in,
                              void* d_out, int out_size, void* d_ws, size_t ws_size,
                              hipStream_t stream) {
    const float* x  = (const float*)d_in[0];
    const float* Wf = (const float*)d_in[1];
    const float* bf = (const float*)d_in[2];
    const float* Ws = (const float*)d_in[3];
    const float* bs = (const float*)d_in[4];
    const float* Wo = (const float*)d_in[5];
    const float* bo = (const float*)d_in[6];
    float* outp = (float*)d_out;

    float* ws      = (float*)d_ws;
    float* coords4 = ws;                      // 32768*4  = 131072 floats
    float* feats   = ws + 131072;             // 32768*24 = 786432 floats

    gn_pre<<<(32768 * 4) / 256, 256, 0, stream>>>(x, Wf, bf, Ws, bs, coords4, feats);
    gn_main<<<32768 / (WPB * QW), WPB * 64, 0, stream>>>(x, Wo, bo, coords4, feats, outp);
}